// Round 6
// baseline (345.202 us; speedup 1.0000x reference)
//
#include <hip/hip_runtime.h>
#include <hip/hip_cooperative_groups.h>
#include <hip/hip_bf16.h>
#include <hip/hip_fp16.h>

namespace cg = cooperative_groups;

#define BB 32
#define TT 256
#define MM 16
#define DD 128
#define HH 128
#define GRID 256

typedef unsigned int uint;
typedef unsigned short ushort;

typedef _Float16 f16;
typedef _Float16 f16x8 __attribute__((ext_vector_type(8)));
typedef float f32x4 __attribute__((ext_vector_type(4)));

__device__ __forceinline__ float bl16(uint u){ return __uint_as_float(u << 16); }
__device__ __forceinline__ float bh16(uint u){ return __uint_as_float(u & 0xffff0000u); }

__device__ __forceinline__ float hsig(float x){
  return __builtin_amdgcn_fmed3f(fmaf(x, 0.2f, 0.5f), 0.0f, 1.0f);
}
__device__ __forceinline__ float tanh_f(float x){
  return 1.0f - 2.0f / (__expf(2.0f * x) + 1.0f);   // saturates correctly
}
__device__ __forceinline__ uint packh2(float a, float b){
  __half2 hv = __floats2half2_rn(a, b);
  union{__half2 h; uint x;} cv; cv.h = hv; return cv.x;
}
// quad_perm butterfly: all 4 quad lanes end with the quad sum
__device__ __forceinline__ float qsum4(float v){
  float t1 = __int_as_float(__builtin_amdgcn_mov_dpp(__float_as_int(v), 0xB1, 0xf, 0xf, true));
  v += t1;
  float t2 = __int_as_float(__builtin_amdgcn_mov_dpp(__float_as_int(v), 0x4E, 0xf, 0xf, true));
  return v + t2;
}

// ===================================================================================
// R6: ONE cooperative kernel. Cross-round evidence (R0/R1 5-launch upstream ~144 us,
// R2/R4/R5 4-launch ~126-130 us) puts per-launch overhead at ~17 us while the real
// upstream compute is ~25 us. grid.sync() replaces 3 launch boundaries.
//   phase 0: per-block dtype probe + vx into LDS (no cross-block dep); pack Uw/Ww.
//   phase 1: softmax-pool, 8 passes x 4 tiles/block.           -> newx (f16)
//   sync; phase 2: x-projection, 2048 wave-jobs, MFMA.          -> Xp (f32)
//   sync; phase 3: recurrence (blocks 0-31), R5 step loop verbatim.
// Grid 256 x 512 @ waves_per_eu(2,2) = exactly 1 block/CU -> co-residency guaranteed.
// ===================================================================================
__global__ __attribute__((amdgpu_waves_per_eu(2, 2))) __launch_bounds__(512)
void k_fused(const void* __restrict__ xraw, const void* __restrict__ Wa,
  const void* __restrict__ U0, const void* __restrict__ U1,
  const void* __restrict__ U2, const void* __restrict__ U3,
  const void* __restrict__ W0, const void* __restrict__ W1,
  const void* __restrict__ W2, const void* __restrict__ W3,
  const void* __restrict__ b0_, const void* __restrict__ b1_,
  const void* __restrict__ b2_, const void* __restrict__ b3_,
  uint4* __restrict__ Uw, uint4* __restrict__ Ww,
  __half* __restrict__ newx, float* __restrict__ Xp,
  float* __restrict__ out)
{
  __shared__ float xs[4][MM][DD];                 // 32 KB (pool tiles)
  __shared__ float sc4[4][MM];
  __shared__ __align__(16) float part4[512];
  __shared__ __align__(16) float vxs[DD];
  __shared__ int cnt[256];
  __shared__ int smode;
  __shared__ __align__(16) __half hlds[2][HH];    // recurrence h double-buffer

  cg::grid_group grid = cg::this_grid();
  int tid = threadIdx.x;
  int bid = blockIdx.x;
  int lane = tid & 63;
  int wv = tid >> 6;

  // ---------------- phase 0a: dtype probe (same 2048-sample rule as R5) ----------
  if (tid < 256){
    const ushort* u = (const ushort*)xraw;
    int c = 0;
    #pragma unroll
    for (int j = 0; j < 8; ++j){
      ushort v = u[2 * (tid * 8 + j)];
      float f = __uint_as_float(((uint)v) << 16);
      if (f == f && fabsf(f) < 64.f && fabsf(f) > 1e-12f) ++c;
    }
    cnt[tid] = c;
  }
  __syncthreads();
  if (tid == 0){
    int s = 0;
    for (int i = 0; i < 256; ++i) s += cnt[i];
    smode = (s > 1024) ? 1 : 0;
  }
  __syncthreads();
  int mode = smode;

  // ---------------- phase 0b: pack Uw/Ww MFMA B-frags (gtid < 16384) -------------
  // Frag layout (R3/R4-verified): frag f=(g*4+kc)*8+cb; lane l, elem e: M[k][c],
  // k = kc*32+(l>>4)*8+e, c = cb*16+(l&15).
  {
    int gtid = bid * 512 + tid;
    if (gtid < 16384){
      int half = gtid >> 13;               // 0 -> Uw, 1 -> Ww
      int idx = gtid & 8191;
      int f = idx >> 6, pl = idx & 63;
      int g = f >> 5, kc = (f >> 3) & 3, cb = f & 7;
      int k0 = kc * 32 + (pl >> 4) * 8;
      int c  = cb * 16 + (pl & 15);
      const void* Ms[8] = {U0, U1, U2, U3, W0, W1, W2, W3};
      const void* M = Ms[half * 4 + g];
      float v[8];
      if (mode){
        const ushort* U = (const ushort*)M;
        #pragma unroll
        for (int e = 0; e < 8; ++e)
          v[e] = __uint_as_float(((uint)U[(size_t)(k0 + e) * HH + c]) << 16);
      } else {
        const float* U = (const float*)M;
        #pragma unroll
        for (int e = 0; e < 8; ++e)
          v[e] = U[(size_t)(k0 + e) * HH + c];
      }
      uint4 o;
      o.x = packh2(v[0], v[1]); o.y = packh2(v[2], v[3]);
      o.z = packh2(v[4], v[5]); o.w = packh2(v[6], v[7]);
      (half ? Ww : Uw)[idx] = o;
    }
  }

  // ---------------- phase 0c: vx[d] = sum_h W_a[d][h] into LDS (every block) -----
  {
    int d = tid >> 2, q = tid & 3;       // 32 elems per thread
    float s = 0.f;
    if (mode){
      const uint4* row = (const uint4*)((const ushort*)Wa + d * HH + q * 32);
      #pragma unroll
      for (int qq = 0; qq < 4; ++qq){
        uint4 v = row[qq];
        s += bl16(v.x) + bh16(v.x) + bl16(v.y) + bh16(v.y)
           + bl16(v.z) + bh16(v.z) + bl16(v.w) + bh16(v.w);
      }
    } else {
      const float4* row = (const float4*)((const float*)Wa + d * HH + q * 32);
      #pragma unroll
      for (int qq = 0; qq < 8; ++qq){
        float4 v = row[qq];
        s += v.x + v.y + v.z + v.w;
      }
    }
    part4[tid] = s;
  }
  __syncthreads();
  if (tid < 128)
    vxs[tid] = part4[4 * tid] + part4[4 * tid + 1] + part4[4 * tid + 2] + part4[4 * tid + 3];

  // ---------------- phase 1: softmax-pool, 8 passes x 4 tiles ---------------------
  for (int pass = 0; pass < 8; ++pass){
    int q4 = tid >> 7, t2 = tid & 127;
    int bt = pass * 1024 + bid * 4 + q4;     // tile 0..8191
    int b = bt >> 8, t = bt & 255;
    float* xdst = &xs[q4][0][0];
    __syncthreads();                          // WAR on xs/sc4 from previous pass
    if (mode){
      const float* vxp = &vxs[(t2 & 15) * 8];
      float4 vra = *(const float4*)vxp;
      float4 vrb = *(const float4*)(vxp + 4);
      const uint4* s = (const uint4*)((const ushort*)xraw + (size_t)bt * 2048);
      float sq[2];
      #pragma unroll
      for (int q = 0; q < 2; ++q){
        int ch = t2 + 128 * q;
        uint4 v = s[ch];
        float* d = &xdst[ch * 8];
        float e0 = bl16(v.x), e1 = bh16(v.x), e2 = bl16(v.y), e3 = bh16(v.y);
        float e4 = bl16(v.z), e5 = bh16(v.z), e6 = bl16(v.w), e7 = bh16(v.w);
        d[0] = e0; d[1] = e1; d[2] = e2; d[3] = e3;
        d[4] = e4; d[5] = e5; d[6] = e6; d[7] = e7;
        float p = e0 * vra.x;
        p = fmaf(e1, vra.y, p); p = fmaf(e2, vra.z, p); p = fmaf(e3, vra.w, p);
        p = fmaf(e4, vrb.x, p); p = fmaf(e5, vrb.y, p); p = fmaf(e6, vrb.z, p);
        p = fmaf(e7, vrb.w, p);
        sq[q] = p;
      }
      #pragma unroll
      for (int q = 0; q < 2; ++q){
        float v = qsum4(sq[q]);
        v += __shfl_xor(v, 4, 16);
        v += __shfl_xor(v, 8, 16);
        sq[q] = v;
      }
      if ((t2 & 15) == 0){
        sc4[q4][t2 >> 4]       = sq[0];
        sc4[q4][(t2 >> 4) + 8] = sq[1];
      }
    } else {
      float4 vra = *(const float4*)&vxs[(t2 & 31) * 4];
      const float4* s = (const float4*)((const float*)xraw + (size_t)bt * 2048);
      float sq[4];
      #pragma unroll
      for (int q = 0; q < 4; ++q){
        int ch = t2 + 128 * q;
        float4 v = s[ch];
        *(float4*)&xdst[ch * 4] = v;
        float p = v.x * vra.x;
        p = fmaf(v.y, vra.y, p); p = fmaf(v.z, vra.z, p); p = fmaf(v.w, vra.w, p);
        sq[q] = p;
      }
      #pragma unroll
      for (int q = 0; q < 4; ++q){
        float v = qsum4(sq[q]);
        v += __shfl_xor(v, 4, 32);
        v += __shfl_xor(v, 8, 32);
        v += __shfl_xor(v, 16, 32);
        sq[q] = v;
      }
      if ((t2 & 31) == 0){
        int mb = t2 >> 5;
        sc4[q4][mb]      = sq[0];
        sc4[q4][mb + 4]  = sq[1];
        sc4[q4][mb + 8]  = sq[2];
        sc4[q4][mb + 12] = sq[3];
      }
    }
    __syncthreads();

    float mx = sc4[q4][0];
    #pragma unroll
    for (int m2 = 1; m2 < MM; ++m2) mx = fmaxf(mx, sc4[q4][m2]);
    float wgt[MM]; float den = 0.f;
    #pragma unroll
    for (int m2 = 0; m2 < MM; ++m2){ wgt[m2] = __expf(sc4[q4][m2] - mx); den += wgt[m2]; }
    float inv = 1.0f / den;

    float acc = 0.f;
    #pragma unroll
    for (int m2 = 0; m2 < MM; ++m2)
      acc = fmaf(wgt[m2], xs[q4][m2][t2], acc);
    newx[((size_t)t * BB + b) * DD + t2] = __float2half(acc * inv);
  }

  grid.sync();

  // ---------------- phase 2: x-projection, 2048 wave-jobs -------------------------
  // job wg = bid*8+wv: rows rc*16..rc*16+15 (rc=wg>>2), gate G=wg&3, all 128 cols.
  // A-frags read DIRECTLY from newx (16B/lane/kc, L2/L3-hot); no LDS, no barrier.
  {
    int wg = bid * 8 + wv;
    int rc = wg >> 2, G = wg & 3;
    int r0 = rc * 16;
    int l16 = lane & 15, lq = lane >> 4;

    const void* bb = (G == 0) ? b0_ : (G == 1) ? b1_ : (G == 2) ? b2_ : b3_;
    float bias[8];
    #pragma unroll
    for (int cb = 0; cb < 8; ++cb){
      int col = cb * 16 + l16;
      bias[cb] = mode ? __uint_as_float(((uint)((const ushort*)bb)[col]) << 16)
                      : ((const float*)bb)[col];
    }

    f16x8 a[4];
    #pragma unroll
    for (int kc = 0; kc < 4; ++kc)
      a[kc] = *(const f16x8*)(newx + (size_t)(r0 + l16) * DD + kc * 32 + lq * 8);

    f32x4 acc[8];
    #pragma unroll
    for (int cb = 0; cb < 8; ++cb)
      acc[cb] = (f32x4){bias[cb], bias[cb], bias[cb], bias[cb]};

    #pragma unroll
    for (int kc = 0; kc < 4; ++kc)
      #pragma unroll
      for (int cb = 0; cb < 8; ++cb){
        union{uint4 u; f16x8 h;} bv;
        bv.u = Ww[((size_t)((G * 4 + kc) * 8 + cb)) * 64 + lane];
        acc[cb] = __builtin_amdgcn_mfma_f32_16x16x32_f16(a[kc], bv.h, acc[cb], 0, 0, 0);
      }

    #pragma unroll
    for (int cb = 0; cb < 8; ++cb)
      #pragma unroll
      for (int reg = 0; reg < 4; ++reg)
        Xp[(size_t)(r0 + lq * 4 + reg) * 512 + G * HH + cb * 16 + l16] = acc[cb][reg];
  }

  grid.sync();

  // ---------------- phase 3: recurrence (blocks 0-31), R5 loop verbatim ----------
  if (bid < BB){
    int b = bid;
    int l16 = lane & 15;

    f16x8 Ub[16];
    #pragma unroll
    for (int g = 0; g < 4; ++g)
      #pragma unroll
      for (int kc = 0; kc < 4; ++kc){
        uint4 v = Uw[((g * 4 + kc) * 8 + wv) * 64 + lane];
        union{uint4 u; f16x8 h;} cv; cv.u = v;
        Ub[g * 4 + kc] = cv.h;
      }

    const float* xcol = Xp + (size_t)b * 512 + wv * 16 + l16;
    float xpA[4], xpB[4];
    #pragma unroll
    for (int g = 0; g < 4; ++g) xpA[g] = xcol[g * 128];
    #pragma unroll
    for (int g = 0; g < 4; ++g) xpB[g] = xcol[(size_t)(BB * 512) + g * 128];

    if (tid < 64) ((uint*)&hlds[0][0])[tid] = 0;
    float cst = 0.f, vh = 0.f;
    const int lo = (lane >> 4) * 16;
    __syncthreads();

#define STEP(T, XP) do{                                                        \
    const char* hb = (const char*)&hlds[(T) & 1][0];                           \
    f16x8 a0 = *(const f16x8*)(hb +   0 + lo);                                 \
    f16x8 a1 = *(const f16x8*)(hb +  64 + lo);                                 \
    f16x8 a2 = *(const f16x8*)(hb + 128 + lo);                                 \
    f16x8 a3 = *(const f16x8*)(hb + 192 + lo);                                 \
    f32x4 c0, c1, c2, c3, d0, d1, d2, d3;                                      \
    c0[0] = XP[0]; c1[0] = XP[1]; c2[0] = XP[2]; c3[0] = XP[3];                \
    d0[0] = 0.f;   d1[0] = 0.f;   d2[0] = 0.f;   d3[0] = 0.f;                  \
    c0 = __builtin_amdgcn_mfma_f32_16x16x32_f16(a0, Ub[ 0], c0, 0, 0, 0);      \
    c1 = __builtin_amdgcn_mfma_f32_16x16x32_f16(a0, Ub[ 4], c1, 0, 0, 0);      \
    c2 = __builtin_amdgcn_mfma_f32_16x16x32_f16(a0, Ub[ 8], c2, 0, 0, 0);      \
    c3 = __builtin_amdgcn_mfma_f32_16x16x32_f16(a0, Ub[12], c3, 0, 0, 0);      \
    d0 = __builtin_amdgcn_mfma_f32_16x16x32_f16(a2, Ub[ 2], d0, 0, 0, 0);      \
    d1 = __builtin_amdgcn_mfma_f32_16x16x32_f16(a2, Ub[ 6], d1, 0, 0, 0);      \
    d2 = __builtin_amdgcn_mfma_f32_16x16x32_f16(a2, Ub[10], d2, 0, 0, 0);      \
    d3 = __builtin_amdgcn_mfma_f32_16x16x32_f16(a2, Ub[14], d3, 0, 0, 0);      \
    c0 = __builtin_amdgcn_mfma_f32_16x16x32_f16(a1, Ub[ 1], c0, 0, 0, 0);      \
    c1 = __builtin_amdgcn_mfma_f32_16x16x32_f16(a1, Ub[ 5], c1, 0, 0, 0);      \
    c2 = __builtin_amdgcn_mfma_f32_16x16x32_f16(a1, Ub[ 9], c2, 0, 0, 0);      \
    c3 = __builtin_amdgcn_mfma_f32_16x16x32_f16(a1, Ub[13], c3, 0, 0, 0);      \
    d0 = __builtin_amdgcn_mfma_f32_16x16x32_f16(a3, Ub[ 3], d0, 0, 0, 0);      \
    d1 = __builtin_amdgcn_mfma_f32_16x16x32_f16(a3, Ub[ 7], d1, 0, 0, 0);      \
    d2 = __builtin_amdgcn_mfma_f32_16x16x32_f16(a3, Ub[11], d2, 0, 0, 0);      \
    d3 = __builtin_amdgcn_mfma_f32_16x16x32_f16(a3, Ub[15], d3, 0, 0, 0);      \
    float p0 = c0[0] + d0[0];                                                  \
    float p1 = c1[0] + d1[0];                                                  \
    float p2 = c2[0] + d2[0];                                                  \
    float p3 = c3[0] + d3[0];                                                  \
    float ig = hsig(p0), fg = hsig(p1), og = hsig(p3);                         \
    float gg = tanh_f(p2);                                                     \
    cst = fmaf(fg, cst, ig * gg);                                              \
    vh  = og * tanh_f(cst);                                                    \
    if (lane < 16) hlds[((T) + 1) & 1][wv * 16 + lane] = __float2half(vh);     \
    {                                                                          \
      int tp = (T) + 2; if (tp > TT - 1) tp = TT - 1;                          \
      const float* xsrc = xcol + ((size_t)tp << 14);                           \
      _Pragma("unroll")                                                        \
      for (int g = 0; g < 4; ++g) XP[g] = xsrc[g * 128];                       \
    }                                                                          \
    asm volatile("s_waitcnt lgkmcnt(0)" ::: "memory");                         \
    __builtin_amdgcn_s_barrier();                                              \
    asm volatile("" ::: "memory");                                             \
  }while(0)

    for (int t = 0; t < TT; t += 2){
      STEP(t,     xpA);
      STEP(t + 1, xpB);
    }
#undef STEP

    if (lane < 16) out[b * HH + wv * 16 + lane] = vh;
  }
}

// ===================================================================================
// Fallback path (R5 kernels, 4 launches) — used only if cooperative launch fails.
// ===================================================================================
__global__ __launch_bounds__(256) void k_prep(
  const void* __restrict__ xraw, const void* __restrict__ Wa,
  const void* __restrict__ U0, const void* __restrict__ U1,
  const void* __restrict__ U2, const void* __restrict__ U3,
  const void* __restrict__ W0, const void* __restrict__ W1,
  const void* __restrict__ W2, const void* __restrict__ W3,
  int* __restrict__ flag, float* __restrict__ vx,
  uint4* __restrict__ Uw, uint4* __restrict__ Ww)
{
  __shared__ int cnt[256];
  __shared__ int smode;
  int tid = threadIdx.x;
  int bid = blockIdx.x;
  {
    const ushort* u = (const ushort*)xraw;
    int c = 0;
    #pragma unroll
    for (int j = 0; j < 8; ++j){
      ushort v = u[2 * (tid * 8 + j)];
      float f = __uint_as_float(((uint)v) << 16);
      if (f == f && fabsf(f) < 64.f && fabsf(f) > 1e-12f) ++c;
    }
    cnt[tid] = c;
    __syncthreads();
    if (tid == 0){
      int s = 0;
      for (int i = 0; i < 256; ++i) s += cnt[i];
      smode = (s > 1024) ? 1 : 0;
    }
    __syncthreads();
  }
  int mode = smode;

  if (bid < 64){
    int idx = (bid & 31) * 256 + tid;
    int f = idx >> 6, lane = idx & 63;
    int g = f >> 5, kc = (f >> 3) & 3, cb = f & 7;
    int k0 = kc * 32 + (lane >> 4) * 8;
    int c  = cb * 16 + (lane & 15);
    const void* Ms[4];
    if (bid < 32){ Ms[0] = U0; Ms[1] = U1; Ms[2] = U2; Ms[3] = U3; }
    else         { Ms[0] = W0; Ms[1] = W1; Ms[2] = W2; Ms[3] = W3; }
    float v[8];
    if (mode){
      const ushort* U = (const ushort*)Ms[g];
      #pragma unroll
      for (int e = 0; e < 8; ++e)
        v[e] = __uint_as_float(((uint)U[(size_t)(k0 + e) * HH + c]) << 16);
    } else {
      const float* U = (const float*)Ms[g];
      #pragma unroll
      for (int e = 0; e < 8; ++e)
        v[e] = U[(size_t)(k0 + e) * HH + c];
    }
    uint4 o;
    o.x = packh2(v[0], v[1]); o.y = packh2(v[2], v[3]);
    o.z = packh2(v[4], v[5]); o.w = packh2(v[6], v[7]);
    ((bid < 32) ? Uw : Ww)[idx] = o;
  } else {
    if (tid == 0) *flag = mode;
    if (tid < 128){
      int d = tid;
      float s = 0.f;
      if (mode){
        const uint4* row = (const uint4*)((const ushort*)Wa + d * HH);
        #pragma unroll
        for (int q = 0; q < 16; ++q){
          uint4 v = row[q];
          s += bl16(v.x) + bh16(v.x) + bl16(v.y) + bh16(v.y)
             + bl16(v.z) + bh16(v.z) + bl16(v.w) + bh16(v.w);
        }
      } else {
        const float4* row = (const float4*)((const float*)Wa + d * HH);
        #pragma unroll
        for (int q = 0; q < 32; ++q){
          float4 v = row[q];
          s += v.x + v.y + v.z + v.w;
        }
      }
      vx[d] = s;
    }
  }
}

__global__ __launch_bounds__(256) void k_pool(const void* __restrict__ xraw,
                                              const int* __restrict__ flag,
                                              const float* __restrict__ vx,
                                              __half* __restrict__ newx){
  __shared__ float xs[2][MM][DD];
  __shared__ float sc[2][MM];
  int mode = *flag;
  int tid = threadIdx.x;
  int half = tid >> 7, t2 = tid & 127;
  int bt = blockIdx.x * 2 + half;
  int b = bt >> 8, t = bt & 255;

  float* xdst = &xs[half][0][0];
  if (mode){
    const float* vxp = vx + (t2 & 15) * 8;
    float4 vra = *(const float4*)vxp;
    float4 vrb = *(const float4*)(vxp + 4);
    const uint4* s = (const uint4*)((const ushort*)xraw + (size_t)bt * 2048);
    float sq[2];
    #pragma unroll
    for (int q = 0; q < 2; ++q){
      int ch = t2 + 128 * q;
      uint4 v = s[ch];
      float* d = &xdst[ch * 8];
      float e0 = bl16(v.x), e1 = bh16(v.x), e2 = bl16(v.y), e3 = bh16(v.y);
      float e4 = bl16(v.z), e5 = bh16(v.z), e6 = bl16(v.w), e7 = bh16(v.w);
      d[0] = e0; d[1] = e1; d[2] = e2; d[3] = e3;
      d[4] = e4; d[5] = e5; d[6] = e6; d[7] = e7;
      float p = e0 * vra.x;
      p = fmaf(e1, vra.y, p); p = fmaf(e2, vra.z, p); p = fmaf(e3, vra.w, p);
      p = fmaf(e4, vrb.x, p); p = fmaf(e5, vrb.y, p); p = fmaf(e6, vrb.z, p);
      p = fmaf(e7, vrb.w, p);
      sq[q] = p;
    }
    #pragma unroll
    for (int q = 0; q < 2; ++q){
      float v = qsum4(sq[q]);
      v += __shfl_xor(v, 4, 16);
      v += __shfl_xor(v, 8, 16);
      sq[q] = v;
    }
    if ((t2 & 15) == 0){
      sc[half][t2 >> 4]       = sq[0];
      sc[half][(t2 >> 4) + 8] = sq[1];
    }
  } else {
    float4 vra = *(const float4*)(vx + (t2 & 31) * 4);
    const float4* s = (const float4*)((const float*)xraw + (size_t)bt * 2048);
    float sq[4];
    #pragma unroll
    for (int q = 0; q < 4; ++q){
      int ch = t2 + 128 * q;
      float4 v = s[ch];
      *(float4*)&xdst[ch * 4] = v;
      float p = v.x * vra.x;
      p = fmaf(v.y, vra.y, p); p = fmaf(v.z, vra.z, p); p = fmaf(v.w, vra.w, p);
      sq[q] = p;
    }
    #pragma unroll
    for (int q = 0; q < 4; ++q){
      float v = qsum4(sq[q]);
      v += __shfl_xor(v, 4, 32);
      v += __shfl_xor(v, 8, 32);
      v += __shfl_xor(v, 16, 32);
      sq[q] = v;
    }
    if ((t2 & 31) == 0){
      int mb = t2 >> 5;
      sc[half][mb]      = sq[0];
      sc[half][mb + 4]  = sq[1];
      sc[half][mb + 8]  = sq[2];
      sc[half][mb + 12] = sq[3];
    }
  }
  __syncthreads();

  float mx = sc[half][0];
  #pragma unroll
  for (int m2 = 1; m2 < MM; ++m2) mx = fmaxf(mx, sc[half][m2]);
  float wgt[MM]; float den = 0.f;
  #pragma unroll
  for (int m2 = 0; m2 < MM; ++m2){ wgt[m2] = __expf(sc[half][m2] - mx); den += wgt[m2]; }
  float inv = 1.0f / den;

  float acc = 0.f;
  #pragma unroll
  for (int m2 = 0; m2 < MM; ++m2)
    acc = fmaf(wgt[m2], xs[half][m2][t2], acc);
  newx[((size_t)t * BB + b) * DD + t2] = __float2half(acc * inv);
}

__global__ __launch_bounds__(256) void k_xproj(const __half* __restrict__ nx,
  const uint4* __restrict__ Ww,
  const void* __restrict__ b0_, const void* __restrict__ b1_,
  const void* __restrict__ b2_, const void* __restrict__ b3_,
  const int* __restrict__ flag, float* __restrict__ Xp)
{
  __shared__ __align__(16) char As[32768];
  int tid = threadIdx.x;
  int r0 = blockIdx.x * 128;
  int G  = blockIdx.y;
  int lane = tid & 63, w = tid >> 6;
  int l16 = lane & 15, lq = lane >> 4;

  {
    const uint4* src = (const uint4*)(nx + (size_t)r0 * DD);
    uint4* dst = (uint4*)As;
    #pragma unroll
    for (int i = 0; i < 8; ++i){
      int gid = i * 256 + tid;
      int r = gid >> 4, c16 = gid & 15;
      dst[r * 16 + (c16 ^ (r & 15))] = src[gid];
    }
  }

  int mode = *flag;
  const void* bb = (G == 0) ? b0_ : (G == 1) ? b1_ : (G == 2) ? b2_ : b3_;
  float bias[8];
  #pragma unroll
  for (int cb = 0; cb < 8; ++cb){
    int col = cb * 16 + l16;
    bias[cb] = mode ? __uint_as_float(((uint)((const ushort*)bb)[col]) << 16)
                    : ((const float*)bb)[col];
  }
  __syncthreads();

  int rb = w * 32;
  f32x4 acc[2][8];
  #pragma unroll
  for (int mt = 0; mt < 2; ++mt)
    #pragma unroll
    for (int cb = 0; cb < 8; ++cb)
      acc[mt][cb] = (f32x4){bias[cb], bias[cb], bias[cb], bias[cb]};

  #pragma unroll
  for (int kc = 0; kc < 4; ++kc){
    f16x8 a[2];
    #pragma unroll
    for (int mt = 0; mt < 2; ++mt){
      int r = rb + mt * 16 + l16;
      int g16 = (kc * 4 + lq) ^ (r & 15);
      a[mt] = *(const f16x8*)(As + r * 256 + g16 * 16);
    }
    #pragma unroll
    for (int cb = 0; cb < 8; ++cb){
      union{uint4 u; f16x8 h;} bv;
      bv.u = Ww[((size_t)((G * 4 + kc) * 8 + cb)) * 64 + lane];
      acc[0][cb] = __builtin_amdgcn_mfma_f32_16x16x32_f16(a[0], bv.h, acc[0][cb], 0, 0, 0);
      acc[1][cb] = __builtin_amdgcn_mfma_f32_16x16x32_f16(a[1], bv.h, acc[1][cb], 0, 0, 0);
    }
  }

  #pragma unroll
  for (int mt = 0; mt < 2; ++mt)
    #pragma unroll
    for (int cb = 0; cb < 8; ++cb)
      #pragma unroll
      for (int reg = 0; reg < 4; ++reg){
        size_t r = (size_t)(r0 + rb + mt * 16 + lq * 4 + reg);
        Xp[r * 512 + G * HH + cb * 16 + l16] = acc[mt][cb][reg];
      }
}

__global__ __attribute__((amdgpu_waves_per_eu(2, 2))) __launch_bounds__(512)
void k_rec(const float* __restrict__ Xp, const uint4* __restrict__ Uw,
           float* __restrict__ out)
{
  __shared__ __align__(16) __half hlds[2][HH];
  int tid  = threadIdx.x;
  int b    = blockIdx.x;
  int w    = tid >> 6;
  int lane = tid & 63;
  int l16  = lane & 15;

  f16x8 Ub[16];
  #pragma unroll
  for (int g = 0; g < 4; ++g)
    #pragma unroll
    for (int kc = 0; kc < 4; ++kc){
      uint4 v = Uw[((g * 4 + kc) * 8 + w) * 64 + lane];
      union{uint4 u; f16x8 h;} cv; cv.u = v;
      Ub[g * 4 + kc] = cv.h;
    }

  const float* xcol = Xp + (size_t)b * 512 + w * 16 + l16;
  float xpA[4], xpB[4];
  #pragma unroll
  for (int g = 0; g < 4; ++g) xpA[g] = xcol[g * 128];
  #pragma unroll
  for (int g = 0; g < 4; ++g) xpB[g] = xcol[(size_t)(BB * 512) + g * 128];

  if (tid < 64) ((uint*)&hlds[0][0])[tid] = 0;
  float cst = 0.f, vh = 0.f;
  const int lo = (lane >> 4) * 16;
  __syncthreads();

#define STEP(T, XP) do{                                                        \
    const char* hb = (const char*)&hlds[(T) & 1][0];                           \
    f16x8 a0 = *(const f16x8*)(hb +   0 + lo);                                 \
    f16x8 a1 = *(const f16x8*)(hb +  64 + lo);                                 \
    f16x8 a2 = *(const f16x8*)(hb + 128 + lo);                                 \
    f16x8 a3 = *(const f16x8*)(hb + 192 + lo);                                 \
    f32x4 c0, c1, c2, c3, d0, d1, d2, d3;                                      \
    c0[0] = XP[0]; c1[0] = XP[1]; c2[0] = XP[2]; c3[0] = XP[3];                \
    d0[0] = 0.f;   d1[0] = 0.f;   d2[0] = 0.f;   d3[0] = 0.f;                  \
    c0 = __builtin_amdgcn_mfma_f32_16x16x32_f16(a0, Ub[ 0], c0, 0, 0, 0);      \
    c1 = __builtin_amdgcn_mfma_f32_16x16x32_f16(a0, Ub[ 4], c1, 0, 0, 0);      \
    c2 = __builtin_amdgcn_mfma_f32_16x16x32_f16(a0, Ub[ 8], c2, 0, 0, 0);      \
    c3 = __builtin_amdgcn_mfma_f32_16x16x32_f16(a0, Ub[12], c3, 0, 0, 0);      \
    d0 = __builtin_amdgcn_mfma_f32_16x16x32_f16(a2, Ub[ 2], d0, 0, 0, 0);      \
    d1 = __builtin_amdgcn_mfma_f32_16x16x32_f16(a2, Ub[ 6], d1, 0, 0, 0);      \
    d2 = __builtin_amdgcn_mfma_f32_16x16x32_f16(a2, Ub[10], d2, 0, 0, 0);      \
    d3 = __builtin_amdgcn_mfma_f32_16x16x32_f16(a2, Ub[14], d3, 0, 0, 0);      \
    c0 = __builtin_amdgcn_mfma_f32_16x16x32_f16(a1, Ub[ 1], c0, 0, 0, 0);      \
    c1 = __builtin_amdgcn_mfma_f32_16x16x32_f16(a1, Ub[ 5], c1, 0, 0, 0);      \
    c2 = __builtin_amdgcn_mfma_f32_16x16x32_f16(a1, Ub[ 9], c2, 0, 0, 0);      \
    c3 = __builtin_amdgcn_mfma_f32_16x16x32_f16(a1, Ub[13], c3, 0, 0, 0);      \
    d0 = __builtin_amdgcn_mfma_f32_16x16x32_f16(a3, Ub[ 3], d0, 0, 0, 0);      \
    d1 = __builtin_amdgcn_mfma_f32_16x16x32_f16(a3, Ub[ 7], d1, 0, 0, 0);      \
    d2 = __builtin_amdgcn_mfma_f32_16x16x32_f16(a3, Ub[11], d2, 0, 0, 0);      \
    d3 = __builtin_amdgcn_mfma_f32_16x16x32_f16(a3, Ub[15], d3, 0, 0, 0);      \
    float p0 = c0[0] + d0[0];                                                  \
    float p1 = c1[0] + d1[0];                                                  \
    float p2 = c2[0] + d2[0];                                                  \
    float p3 = c3[0] + d3[0];                                                  \
    float ig = hsig(p0), fg = hsig(p1), og = hsig(p3);                         \
    float gg = tanh_f(p2);                                                     \
    cst = fmaf(fg, cst, ig * gg);                                              \
    vh  = og * tanh_f(cst);                                                    \
    if (lane < 16) hlds[((T) + 1) & 1][w * 16 + lane] = __float2half(vh);      \
    {                                                                          \
      int tp = (T) + 2; if (tp > TT - 1) tp = TT - 1;                          \
      const float* xsrc = xcol + ((size_t)tp << 14);                           \
      _Pragma("unroll")                                                        \
      for (int g = 0; g < 4; ++g) XP[g] = xsrc[g * 128];                       \
    }                                                                          \
    asm volatile("s_waitcnt lgkmcnt(0)" ::: "memory");                         \
    __builtin_amdgcn_s_barrier();                                              \
    asm volatile("" ::: "memory");                                             \
  }while(0)

  for (int t = 0; t < TT; t += 2){
    STEP(t,     xpA);
    STEP(t + 1, xpB);
  }
#undef STEP

  if (lane < 16) out[b * HH + w * 16 + lane] = vh;
}

extern "C" void kernel_launch(void* const* d_in, const int* in_sizes, int n_in,
                              void* d_out, int out_size, void* d_ws, size_t ws_size,
                              hipStream_t stream) {
  (void)in_sizes; (void)n_in; (void)out_size; (void)ws_size;

  // ---- workspace layout (both paths share it, ~18.4 MB) ----
  // [0,16) flag | [16,528) vx | [1024,+128K) Uw | [+128K) Ww | [+2M) newx | [+16M) Xp
  char* ws = (char*)d_ws;
  int* flag = (int*)ws;
  float* vx = (float*)(ws + 16);
  uint4* Uw = (uint4*)(ws + 1024);
  uint4* Ww = (uint4*)(ws + 1024 + 131072);
  __half* newx = (__half*)(ws + 1024 + 2 * 131072);
  float* Xp = (float*)(ws + 1024 + 2 * 131072 + (size_t)2 * 1024 * 1024);

  void* p_x  = (void*)d_in[0];  void* p_wa = (void*)d_in[1];
  void* p_u0 = (void*)d_in[4];  void* p_u1 = (void*)d_in[7];
  void* p_u2 = (void*)d_in[10]; void* p_u3 = (void*)d_in[13];
  void* p_w0 = (void*)d_in[3];  void* p_w1 = (void*)d_in[6];
  void* p_w2 = (void*)d_in[9];  void* p_w3 = (void*)d_in[12];
  void* p_b0 = (void*)d_in[5];  void* p_b1 = (void*)d_in[8];
  void* p_b2 = (void*)d_in[11]; void* p_b3 = (void*)d_in[14];
  void* p_out = d_out;

  void* kargs[] = {
    &p_x, &p_wa,
    &p_u0, &p_u1, &p_u2, &p_u3,
    &p_w0, &p_w1, &p_w2, &p_w3,
    &p_b0, &p_b1, &p_b2, &p_b3,
    &Uw, &Ww, &newx, &Xp, &p_out
  };

  hipError_t err = hipLaunchCooperativeKernel(
      reinterpret_cast<const void*>(&k_fused),
      dim3(GRID), dim3(512), kargs, 0, stream);

  if (err != hipSuccess){
    // fallback: proven R5 4-launch path
    k_prep<<<65, 256, 0, stream>>>(d_in[0], d_in[1],
        d_in[4], d_in[7], d_in[10], d_in[13],
        d_in[3], d_in[6], d_in[9],  d_in[12],
        flag, vx, Uw, Ww);
    k_pool<<<BB * TT / 2, 256, 0, stream>>>(d_in[0], flag, vx, newx);
    dim3 g2(64, 4);
    k_xproj<<<g2, 256, 0, stream>>>(newx, Ww,
        d_in[5], d_in[8], d_in[11], d_in[14],
        flag, Xp);
    k_rec<<<BB, 512, 0, stream>>>(Xp, Uw, (float*)d_out);
  }
}

// Round 7
// 292.767 us; speedup vs baseline: 1.1791x; 1.1791x over previous
//
#include <hip/hip_runtime.h>
#include <hip/hip_bf16.h>
#include <hip/hip_fp16.h>

#define BB 32
#define TT 256
#define MM 16
#define DD 128
#define HH 128

typedef unsigned int uint;
typedef unsigned short ushort;

typedef _Float16 f16;
typedef _Float16 f16x8 __attribute__((ext_vector_type(8)));
typedef float f32x4 __attribute__((ext_vector_type(4)));

__device__ __forceinline__ float bl16(uint u){ return __uint_as_float(u << 16); }
__device__ __forceinline__ float bh16(uint u){ return __uint_as_float(u & 0xffff0000u); }

__device__ __forceinline__ float hsig(float x){
  return __builtin_amdgcn_fmed3f(fmaf(x, 0.2f, 0.5f), 0.0f, 1.0f);
}
__device__ __forceinline__ float tanh_f(float x){
  return 1.0f - 2.0f / (__expf(2.0f * x) + 1.0f);   // saturates correctly
}
__device__ __forceinline__ uint packh2(float a, float b){
  __half2 hv = __floats2half2_rn(a, b);
  union{__half2 h; uint x;} cv; cv.h = hv; return cv.x;
}
// quad_perm butterfly: all 4 quad lanes end with the quad sum
__device__ __forceinline__ float qsum4(float v){
  float t1 = __int_as_float(__builtin_amdgcn_mov_dpp(__float_as_int(v), 0xB1, 0xf, 0xf, true));
  v += t1;
  float t2 = __int_as_float(__builtin_amdgcn_mov_dpp(__float_as_int(v), 0x4E, 0xf, 0xf, true));
  return v + t2;
}

// ===================================================================================
// R7: 4 -> 2 regular launches (coop launch refuted in R6: ~130us non-capturable
// overhead; regular launch boundary ~15us each, twice-measured).
//   Launch 1 k_prep_pool (4160 blocks): bid<64 pack Uw/Ww; else softmax-pool with
//     self-probed dtype + self-computed vx (Wa is L2-hot; no cross-block dep).
//   Launch 2 k_rec2 (32 blocks): PROLOGUE computes this block's own Xp slice
//     (rows t*32+b) via f16 MFMA from newx/Ww (R3/R4-verified frag maps), writes
//     global Xp, vmcnt(0)+barrier, then the R5 recurrence loop verbatim.
// ===================================================================================

// ---------------- Launch 1: prep + pool ---------------------------------------------
__global__ __launch_bounds__(256) void k_prep_pool(
  const void* __restrict__ xraw, const void* __restrict__ Wa,
  const void* __restrict__ U0, const void* __restrict__ U1,
  const void* __restrict__ U2, const void* __restrict__ U3,
  const void* __restrict__ W0, const void* __restrict__ W1,
  const void* __restrict__ W2, const void* __restrict__ W3,
  uint4* __restrict__ Uw, uint4* __restrict__ Ww,
  __half* __restrict__ newx)
{
  __shared__ float xs[2][MM][DD];   // 16 KB
  __shared__ float sc[2][MM];
  __shared__ __align__(16) float vxs[DD];
  __shared__ int wcnt[4];
  __shared__ int smode;
  int tid = threadIdx.x;
  int bid = blockIdx.x;

  // ---- dtype probe: same 2048-sample rule, wave-reduced (cheap) ----
  {
    const ushort* u = (const ushort*)xraw;
    int c = 0;
    #pragma unroll
    for (int j = 0; j < 8; ++j){
      ushort v = u[2 * (tid * 8 + j)];
      float f = __uint_as_float(((uint)v) << 16);
      if (f == f && fabsf(f) < 64.f && fabsf(f) > 1e-12f) ++c;
    }
    #pragma unroll
    for (int off = 1; off < 64; off <<= 1) c += __shfl_xor(c, off, 64);
    if ((tid & 63) == 0) wcnt[tid >> 6] = c;
    __syncthreads();
    if (tid == 0) smode = (wcnt[0] + wcnt[1] + wcnt[2] + wcnt[3] > 1024) ? 1 : 0;
    __syncthreads();
  }
  int mode = smode;

  if (bid < 64){
    // ---- pack one quartet element (R5 k_prep, verified) ----
    int idx = (bid & 31) * 256 + tid;      // 0..8191
    int f = idx >> 6, lane = idx & 63;
    int g = f >> 5, kc = (f >> 3) & 3, cb = f & 7;
    int k0 = kc * 32 + (lane >> 4) * 8;
    int c  = cb * 16 + (lane & 15);
    const void* Ms[4];
    if (bid < 32){ Ms[0] = U0; Ms[1] = U1; Ms[2] = U2; Ms[3] = U3; }
    else         { Ms[0] = W0; Ms[1] = W1; Ms[2] = W2; Ms[3] = W3; }
    float v[8];
    if (mode){
      const ushort* U = (const ushort*)Ms[g];
      #pragma unroll
      for (int e = 0; e < 8; ++e)
        v[e] = __uint_as_float(((uint)U[(size_t)(k0 + e) * HH + c]) << 16);
    } else {
      const float* U = (const float*)Ms[g];
      #pragma unroll
      for (int e = 0; e < 8; ++e)
        v[e] = U[(size_t)(k0 + e) * HH + c];
    }
    uint4 o;
    o.x = packh2(v[0], v[1]); o.y = packh2(v[2], v[3]);
    o.z = packh2(v[4], v[5]); o.w = packh2(v[6], v[7]);
    ((bid < 32) ? Uw : Ww)[idx] = o;
    return;
  }

  // ---- vx self-compute: vx[d] = sum_h Wa[d][h]; Wa is 64KB, L2-hot ----
  {
    int d = tid >> 1, q = tid & 1;       // 64 elems per thread
    float s = 0.f;
    if (mode){
      const uint4* row = (const uint4*)((const ushort*)Wa + d * HH + q * 64);
      #pragma unroll
      for (int qq = 0; qq < 8; ++qq){
        uint4 v = row[qq];
        s += bl16(v.x) + bh16(v.x) + bl16(v.y) + bh16(v.y)
           + bl16(v.z) + bh16(v.z) + bl16(v.w) + bh16(v.w);
      }
    } else {
      const float4* row = (const float4*)((const float*)Wa + d * HH + q * 64);
      #pragma unroll
      for (int qq = 0; qq < 16; ++qq){
        float4 v = row[qq];
        s += v.x + v.y + v.z + v.w;
      }
    }
    s += __shfl_xor(s, 1, 64);           // pair (2d, 2d+1)
    if (q == 0) vxs[d] = s;
  }
  __syncthreads();

  // ---- softmax-pool (R5 k_pool, verified), vx from LDS ----
  int half = tid >> 7, t2 = tid & 127;
  int bt = (bid - 64) * 2 + half;       // tile 0..8191
  int b = bt >> 8, t = bt & 255;

  float* xdst = &xs[half][0][0];
  if (mode){
    const float* vxp = &vxs[(t2 & 15) * 8];
    float4 vra = *(const float4*)vxp;
    float4 vrb = *(const float4*)(vxp + 4);
    const uint4* s = (const uint4*)((const ushort*)xraw + (size_t)bt * 2048);
    float sq[2];
    #pragma unroll
    for (int q = 0; q < 2; ++q){
      int ch = t2 + 128 * q;
      uint4 v = s[ch];
      float* d = &xdst[ch * 8];
      float e0 = bl16(v.x), e1 = bh16(v.x), e2 = bl16(v.y), e3 = bh16(v.y);
      float e4 = bl16(v.z), e5 = bh16(v.z), e6 = bl16(v.w), e7 = bh16(v.w);
      d[0] = e0; d[1] = e1; d[2] = e2; d[3] = e3;
      d[4] = e4; d[5] = e5; d[6] = e6; d[7] = e7;
      float p = e0 * vra.x;
      p = fmaf(e1, vra.y, p); p = fmaf(e2, vra.z, p); p = fmaf(e3, vra.w, p);
      p = fmaf(e4, vrb.x, p); p = fmaf(e5, vrb.y, p); p = fmaf(e6, vrb.z, p);
      p = fmaf(e7, vrb.w, p);
      sq[q] = p;
    }
    #pragma unroll
    for (int q = 0; q < 2; ++q){
      float v = qsum4(sq[q]);
      v += __shfl_xor(v, 4, 16);
      v += __shfl_xor(v, 8, 16);
      sq[q] = v;
    }
    if ((t2 & 15) == 0){
      sc[half][t2 >> 4]       = sq[0];
      sc[half][(t2 >> 4) + 8] = sq[1];
    }
  } else {
    float4 vra = *(const float4*)&vxs[(t2 & 31) * 4];
    const float4* s = (const float4*)((const float*)xraw + (size_t)bt * 2048);
    float sq[4];
    #pragma unroll
    for (int q = 0; q < 4; ++q){
      int ch = t2 + 128 * q;
      float4 v = s[ch];
      *(float4*)&xdst[ch * 4] = v;
      float p = v.x * vra.x;
      p = fmaf(v.y, vra.y, p); p = fmaf(v.z, vra.z, p); p = fmaf(v.w, vra.w, p);
      sq[q] = p;
    }
    #pragma unroll
    for (int q = 0; q < 4; ++q){
      float v = qsum4(sq[q]);
      v += __shfl_xor(v, 4, 32);
      v += __shfl_xor(v, 8, 32);
      v += __shfl_xor(v, 16, 32);
      sq[q] = v;
    }
    if ((t2 & 31) == 0){
      int mb = t2 >> 5;
      sc[half][mb]      = sq[0];
      sc[half][mb + 4]  = sq[1];
      sc[half][mb + 8]  = sq[2];
      sc[half][mb + 12] = sq[3];
    }
  }
  __syncthreads();

  float mx = sc[half][0];
  #pragma unroll
  for (int m2 = 1; m2 < MM; ++m2) mx = fmaxf(mx, sc[half][m2]);
  float wgt[MM]; float den = 0.f;
  #pragma unroll
  for (int m2 = 0; m2 < MM; ++m2){ wgt[m2] = __expf(sc[half][m2] - mx); den += wgt[m2]; }
  float inv = 1.0f / den;

  float acc = 0.f;
  #pragma unroll
  for (int m2 = 0; m2 < MM; ++m2)
    acc = fmaf(wgt[m2], xs[half][m2][t2], acc);
  newx[((size_t)t * BB + b) * DD + t2] = __float2half(acc * inv);
}

// ---------------- Launch 2: xproj prologue + recurrence -----------------------------
__global__ __attribute__((amdgpu_waves_per_eu(2, 2))) __launch_bounds__(512)
void k_rec2(const void* __restrict__ xraw, const __half* __restrict__ newx,
            const uint4* __restrict__ Uw, const uint4* __restrict__ Ww,
            const void* __restrict__ b0_, const void* __restrict__ b1_,
            const void* __restrict__ b2_, const void* __restrict__ b3_,
            float* __restrict__ Xp, float* __restrict__ out)
{
  __shared__ __align__(16) __half hlds[2][HH];
  __shared__ int wcnt[8];
  __shared__ int smode;
  int tid  = threadIdx.x;
  int b    = blockIdx.x;
  int wv   = tid >> 6;
  int lane = tid & 63;
  int l16  = lane & 15, lq = lane >> 4;

  // ---- dtype probe: same 2048 samples, 4 per thread ----
  {
    const ushort* u = (const ushort*)xraw;
    int c = 0;
    #pragma unroll
    for (int j = 0; j < 4; ++j){
      ushort v = u[2 * (tid * 4 + j)];
      float f = __uint_as_float(((uint)v) << 16);
      if (f == f && fabsf(f) < 64.f && fabsf(f) > 1e-12f) ++c;
    }
    #pragma unroll
    for (int off = 1; off < 64; off <<= 1) c += __shfl_xor(c, off, 64);
    if (lane == 0) wcnt[wv] = c;
    __syncthreads();
    if (tid == 0){
      int s = 0;
      #pragma unroll
      for (int i = 0; i < 8; ++i) s += wcnt[i];
      smode = (s > 1024) ? 1 : 0;
    }
    __syncthreads();
  }
  int mode = smode;

  // ---- PROLOGUE: Xp rows t*32+b (this block's slice), f16 MFMA GEMM ----
  // wave wv covers t-chunks tc = wv and wv+8 (16 t-rows each), all 4 gates.
  // A-frag (R4-verified row map): lane l row m=l&15 -> t = tc*16 + (l&15);
  //   k = kc*32 + (l>>4)*8 + e  -> f16x8 from newx[(t*32+b)*128 + kc*32 + lq*8].
  // C map (verified): row=(l>>4)*4+reg -> t = tc*16+lq*4+reg, col = cb*16+(l&15).
  {
    int tc0 = wv, tc1 = wv + 8;
    for (int G = 0; G < 4; ++G){
      const void* bb = (G == 0) ? b0_ : (G == 1) ? b1_ : (G == 2) ? b2_ : b3_;
      float bias[8];
      #pragma unroll
      for (int cb = 0; cb < 8; ++cb){
        int col = cb * 16 + l16;
        bias[cb] = mode ? __uint_as_float(((uint)((const ushort*)bb)[col]) << 16)
                        : ((const float*)bb)[col];
      }
      f32x4 acc0[8], acc1[8];
      #pragma unroll
      for (int cb = 0; cb < 8; ++cb){
        acc0[cb] = (f32x4){bias[cb], bias[cb], bias[cb], bias[cb]};
        acc1[cb] = (f32x4){bias[cb], bias[cb], bias[cb], bias[cb]};
      }
      #pragma unroll
      for (int kc = 0; kc < 4; ++kc){
        f16x8 a0 = *(const f16x8*)(newx + ((size_t)(tc0 * 16 + l16) * BB + b) * DD + kc * 32 + lq * 8);
        f16x8 a1 = *(const f16x8*)(newx + ((size_t)(tc1 * 16 + l16) * BB + b) * DD + kc * 32 + lq * 8);
        #pragma unroll
        for (int cb = 0; cb < 8; ++cb){
          union{uint4 u; f16x8 h;} bv;
          bv.u = Ww[((size_t)((G * 4 + kc) * 8 + cb)) * 64 + lane];
          acc0[cb] = __builtin_amdgcn_mfma_f32_16x16x32_f16(a0, bv.h, acc0[cb], 0, 0, 0);
          acc1[cb] = __builtin_amdgcn_mfma_f32_16x16x32_f16(a1, bv.h, acc1[cb], 0, 0, 0);
        }
      }
      #pragma unroll
      for (int cb = 0; cb < 8; ++cb)
        #pragma unroll
        for (int reg = 0; reg < 4; ++reg){
          int t0 = tc0 * 16 + lq * 4 + reg;
          int t1 = tc1 * 16 + lq * 4 + reg;
          Xp[((size_t)t0 * BB + b) * 512 + G * HH + cb * 16 + l16] = acc0[cb][reg];
          Xp[((size_t)t1 * BB + b) * 512 + G * HH + cb * 16 + l16] = acc1[cb][reg];
        }
    }
  }
  // writes must land before this block reads them back (same-XCD L2; no stale L1
  // lines since these addresses were never read before)
  asm volatile("s_waitcnt vmcnt(0)" ::: "memory");
  __syncthreads();

  // ---- R5 recurrence loop (verbatim) ----
  f16x8 Ub[16];
  #pragma unroll
  for (int g = 0; g < 4; ++g)
    #pragma unroll
    for (int kc = 0; kc < 4; ++kc){
      uint4 v = Uw[((g * 4 + kc) * 8 + wv) * 64 + lane];
      union{uint4 u; f16x8 h;} cv; cv.u = v;
      Ub[g * 4 + kc] = cv.h;
    }

  const float* xcol = Xp + (size_t)b * 512 + wv * 16 + l16;
  float xpA[4], xpB[4];
  #pragma unroll
  for (int g = 0; g < 4; ++g) xpA[g] = xcol[g * 128];
  #pragma unroll
  for (int g = 0; g < 4; ++g) xpB[g] = xcol[(size_t)(BB * 512) + g * 128];

  if (tid < 64) ((uint*)&hlds[0][0])[tid] = 0;
  float cst = 0.f, vh = 0.f;
  const int lo = lq * 16;
  __syncthreads();

#define STEP(T, XP) do{                                                        \
    const char* hb = (const char*)&hlds[(T) & 1][0];                           \
    f16x8 a0 = *(const f16x8*)(hb +   0 + lo);                                 \
    f16x8 a1 = *(const f16x8*)(hb +  64 + lo);                                 \
    f16x8 a2 = *(const f16x8*)(hb + 128 + lo);                                 \
    f16x8 a3 = *(const f16x8*)(hb + 192 + lo);                                 \
    f32x4 c0, c1, c2, c3, d0, d1, d2, d3;                                      \
    c0[0] = XP[0]; c1[0] = XP[1]; c2[0] = XP[2]; c3[0] = XP[3];                \
    d0[0] = 0.f;   d1[0] = 0.f;   d2[0] = 0.f;   d3[0] = 0.f;                  \
    c0 = __builtin_amdgcn_mfma_f32_16x16x32_f16(a0, Ub[ 0], c0, 0, 0, 0);      \
    c1 = __builtin_amdgcn_mfma_f32_16x16x32_f16(a0, Ub[ 4], c1, 0, 0, 0);      \
    c2 = __builtin_amdgcn_mfma_f32_16x16x32_f16(a0, Ub[ 8], c2, 0, 0, 0);      \
    c3 = __builtin_amdgcn_mfma_f32_16x16x32_f16(a0, Ub[12], c3, 0, 0, 0);      \
    d0 = __builtin_amdgcn_mfma_f32_16x16x32_f16(a2, Ub[ 2], d0, 0, 0, 0);      \
    d1 = __builtin_amdgcn_mfma_f32_16x16x32_f16(a2, Ub[ 6], d1, 0, 0, 0);      \
    d2 = __builtin_amdgcn_mfma_f32_16x16x32_f16(a2, Ub[10], d2, 0, 0, 0);      \
    d3 = __builtin_amdgcn_mfma_f32_16x16x32_f16(a2, Ub[14], d3, 0, 0, 0);      \
    c0 = __builtin_amdgcn_mfma_f32_16x16x32_f16(a1, Ub[ 1], c0, 0, 0, 0);      \
    c1 = __builtin_amdgcn_mfma_f32_16x16x32_f16(a1, Ub[ 5], c1, 0, 0, 0);      \
    c2 = __builtin_amdgcn_mfma_f32_16x16x32_f16(a1, Ub[ 9], c2, 0, 0, 0);      \
    c3 = __builtin_amdgcn_mfma_f32_16x16x32_f16(a1, Ub[13], c3, 0, 0, 0);      \
    d0 = __builtin_amdgcn_mfma_f32_16x16x32_f16(a3, Ub[ 3], d0, 0, 0, 0);      \
    d1 = __builtin_amdgcn_mfma_f32_16x16x32_f16(a3, Ub[ 7], d1, 0, 0, 0);      \
    d2 = __builtin_amdgcn_mfma_f32_16x16x32_f16(a3, Ub[11], d2, 0, 0, 0);      \
    d3 = __builtin_amdgcn_mfma_f32_16x16x32_f16(a3, Ub[15], d3, 0, 0, 0);      \
    float p0 = c0[0] + d0[0];                                                  \
    float p1 = c1[0] + d1[0];                                                  \
    float p2 = c2[0] + d2[0];                                                  \
    float p3 = c3[0] + d3[0];                                                  \
    float ig = hsig(p0), fg = hsig(p1), og = hsig(p3);                         \
    float gg = tanh_f(p2);                                                     \
    cst = fmaf(fg, cst, ig * gg);                                              \
    vh  = og * tanh_f(cst);                                                    \
    if (lane < 16) hlds[((T) + 1) & 1][wv * 16 + lane] = __float2half(vh);     \
    {                                                                          \
      int tp = (T) + 2; if (tp > TT - 1) tp = TT - 1;                          \
      const float* xsrc = xcol + ((size_t)tp << 14);                           \
      _Pragma("unroll")                                                        \
      for (int g = 0; g < 4; ++g) XP[g] = xsrc[g * 128];                       \
    }                                                                          \
    asm volatile("s_waitcnt lgkmcnt(0)" ::: "memory");                         \
    __builtin_amdgcn_s_barrier();                                              \
    asm volatile("" ::: "memory");                                             \
  }while(0)

  for (int t = 0; t < TT; t += 2){
    STEP(t,     xpA);
    STEP(t + 1, xpB);
  }
#undef STEP

  if (lane < 16) out[b * HH + wv * 16 + lane] = vh;
}

extern "C" void kernel_launch(void* const* d_in, const int* in_sizes, int n_in,
                              void* d_out, int out_size, void* d_ws, size_t ws_size,
                              hipStream_t stream) {
  (void)in_sizes; (void)n_in; (void)out_size; (void)ws_size;

  // ---- workspace layout (~18.4 MB) ----
  // [1024, +128KB)    Uw uint4[8192]  (MFMA B-fragments of U, f16)
  // [+, +128KB)       Ww uint4[8192]  (MFMA B-fragments of W, f16)
  // [+, +2MB)         newx f16[8192*128]
  // [+, +16MB)        Xp fp32[8192*512]
  char* ws = (char*)d_ws;
  uint4* Uw = (uint4*)(ws + 1024);
  uint4* Ww = (uint4*)(ws + 1024 + 131072);
  __half* newx = (__half*)(ws + 1024 + 2 * 131072);
  float* Xp = (float*)(ws + 1024 + 2 * 131072 + (size_t)2 * 1024 * 1024);

  k_prep_pool<<<64 + BB * TT / 2, 256, 0, stream>>>(d_in[0], d_in[1],
      d_in[4], d_in[7], d_in[10], d_in[13],    // U_i, U_f, U_c, U_o
      d_in[3], d_in[6], d_in[9],  d_in[12],    // W_i, W_f, W_c, W_o
      Uw, Ww, newx);
  k_rec2<<<BB, 512, 0, stream>>>(d_in[0], newx, Uw, Ww,
      d_in[5], d_in[8], d_in[11], d_in[14],    // b_i, b_f, b_c, b_o
      Xp, (float*)d_out);
}